// Round 1
// baseline (236.803 us; speedup 1.0000x reference)
//
#include <hip/hip_runtime.h>
#include <hip/hip_bf16.h>
#include <math.h>

#define Nn    512
#define CS    384
#define CZ    128
#define CH    16
#define Hh    12
#define PQ    4
#define PV    8
#define NCOL  1152   // 192*3 + 144*2 + 288
#define FIN   2112
#define EXT   28     // 16 + 12

#define W_C   0.23570226039551584f   // sqrt(2/(9*4))
#define W_L   0.5773502691896258f    // sqrt(1/3)

// ---------------- workspace layout (floats) ----------------
#define OFF_P      0u          // N x 1152 raw projections
#define OFF_EXTQ   589824u     // N x H x 28
#define OFF_EXTK   761856u     // N x H x 28
#define OFF_MQ     933888u     // N x H
#define OFF_MK     940032u     // N x H
#define OFF_VPG    946176u     // N x (H*PV*3)=288
#define OFF_FEAT   1093632u    // N x 2112
#define OFF_LOG    2174976u    // N x H x N  (logits -> a in place; later reused as K5 partials)
// total = 5,320,704 floats = 21.3 MB

// ================= K1: projections  P = s_i @ [Wq|Wk|Wv|Wqp|Wkp|Wvp] =========
__global__ __launch_bounds__(384) void k_proj(
    const float* __restrict__ s, const float* __restrict__ Wq,
    const float* __restrict__ Wk, const float* __restrict__ Wv,
    const float* __restrict__ Wqp, const float* __restrict__ Wkp,
    const float* __restrict__ Wvp, float* __restrict__ P) {
  int col = blockIdx.x * 384 + threadIdx.x;       // 0..1151
  int i0  = blockIdx.y * 8;
  const float* base; int stride, off;
  if      (col < 192) { base = Wq;  stride = 192; off = col;       }
  else if (col < 384) { base = Wk;  stride = 192; off = col - 192; }
  else if (col < 576) { base = Wv;  stride = 192; off = col - 384; }
  else if (col < 720) { base = Wqp; stride = 144; off = col - 576; }
  else if (col < 864) { base = Wkp; stride = 144; off = col - 720; }
  else                { base = Wvp; stride = 288; off = col - 864; }
  float acc[8];
#pragma unroll
  for (int ii = 0; ii < 8; ++ii) acc[ii] = 0.f;
  const float* bp = base + off;
#pragma unroll 4
  for (int k = 0; k < CS; ++k) {
    float w = bp[k * stride];
#pragma unroll
    for (int ii = 0; ii < 8; ++ii) acc[ii] += w * s[(i0 + ii) * CS + k];
  }
#pragma unroll
  for (int ii = 0; ii < 8; ++ii) P[(size_t)(i0 + ii) * NCOL + col] = acc[ii];
}

// ============ K1b: rigid transforms + ext vectors + mq/mk + vp_g =============
__global__ __launch_bounds__(64) void k_prep(
    const float* __restrict__ P, const float* __restrict__ rot,
    const float* __restrict__ trans, const float* __restrict__ gamma,
    float* __restrict__ extq, float* __restrict__ extk,
    float* __restrict__ mq, float* __restrict__ mk, float* __restrict__ vpg) {
  int gid = blockIdx.x * 64 + threadIdx.x;        // < 6144
  int i = gid / Hh, h = gid % Hh;
  const float* Pi = P + (size_t)i * NCOL;
  float R[9], T[3];
#pragma unroll
  for (int m = 0; m < 9; ++m) R[m] = rot[i * 9 + m];
#pragma unroll
  for (int m = 0; m < 3; ++m) T[m] = trans[i * 3 + m];
  float cg = W_C * gamma[h];

  float* eq = extq + (size_t)gid * EXT;
  float* ek = extk + (size_t)gid * EXT;
#pragma unroll
  for (int d = 0; d < CH; ++d) eq[d] = Pi[h * CH + d] * 0.25f;       // q/sqrt(16)
#pragma unroll
  for (int d = 0; d < CH; ++d) ek[d] = Pi[192 + h * CH + d];         // k
  float sq = 0.f, sk = 0.f;
#pragma unroll
  for (int p = 0; p < PQ; ++p) {
    float x = Pi[576 + h * 12 + p * 3 + 0];
    float y = Pi[576 + h * 12 + p * 3 + 1];
    float zc = Pi[576 + h * 12 + p * 3 + 2];
    float gx = R[0] * x + R[1] * y + R[2] * zc + T[0];
    float gy = R[3] * x + R[4] * y + R[5] * zc + T[1];
    float gz = R[6] * x + R[7] * y + R[8] * zc + T[2];
    eq[16 + p * 3 + 0] = cg * gx; eq[16 + p * 3 + 1] = cg * gy; eq[16 + p * 3 + 2] = cg * gz;
    sq += gx * gx + gy * gy + gz * gz;
  }
#pragma unroll
  for (int p = 0; p < PQ; ++p) {
    float x = Pi[720 + h * 12 + p * 3 + 0];
    float y = Pi[720 + h * 12 + p * 3 + 1];
    float zc = Pi[720 + h * 12 + p * 3 + 2];
    float gx = R[0] * x + R[1] * y + R[2] * zc + T[0];
    float gy = R[3] * x + R[4] * y + R[5] * zc + T[1];
    float gz = R[6] * x + R[7] * y + R[8] * zc + T[2];
    ek[16 + p * 3 + 0] = gx; ek[16 + p * 3 + 1] = gy; ek[16 + p * 3 + 2] = gz;
    sk += gx * gx + gy * gy + gz * gz;
  }
  mq[gid] = -0.5f * cg * sq;
  mk[gid] = -0.5f * cg * sk;
#pragma unroll
  for (int p = 0; p < PV; ++p) {
    float x = Pi[864 + h * 24 + p * 3 + 0];
    float y = Pi[864 + h * 24 + p * 3 + 1];
    float zc = Pi[864 + h * 24 + p * 3 + 2];
    vpg[(size_t)i * 288 + h * 24 + p * 3 + 0] = R[0] * x + R[1] * y + R[2] * zc + T[0];
    vpg[(size_t)i * 288 + h * 24 + p * 3 + 1] = R[3] * x + R[4] * y + R[5] * zc + T[1];
    vpg[(size_t)i * 288 + h * 24 + p * 3 + 2] = R[6] * x + R[7] * y + R[8] * zc + T[2];
  }
}

// ======== K2: logits[i][h][j] = W_L*( z.Wb + extq.extk + mq + mk ) ===========
__global__ __launch_bounds__(256) void k_logits(
    const float* __restrict__ z, const float* __restrict__ extq,
    const float* __restrict__ extk, const float* __restrict__ mq,
    const float* __restrict__ mk, const float* __restrict__ Wb,
    float* __restrict__ logits) {
  __shared__ float zt[64 * 128];                  // 32 KB, xor-swizzled f4 tiles
  int i = blockIdx.y, j0 = blockIdx.x * 64;
  int tid = threadIdx.x;
  int jl = tid & 63;
  int hg = __builtin_amdgcn_readfirstlane(tid >> 6);   // wave id 0..3 (uniform)
  int h3 = hg * 3;

  // stage z tile: global linear -> LDS swizzled (float4 granularity)
  const float4* zb4 = (const float4*)(z + ((size_t)i * Nn + j0) * CZ);
  float4* zt4 = (float4*)zt;
#pragma unroll
  for (int it = 0; it < 8; ++it) {
    int sidx = it * 256 + tid;                    // 0..2047
    int jj = sidx >> 5, c4 = sidx & 31;
    zt4[jj * 32 + (c4 ^ (jj & 7))] = zb4[sidx];
  }
  __syncthreads();

  int j = j0 + jl;
  float acc[3];
#pragma unroll
  for (int u = 0; u < 3; ++u)
    acc[u] = mq[i * Hh + h3 + u] + mk[j * Hh + h3 + u];

  // b part: 128-dot with Wb columns (Wb via uniform scalar loads)
  const float4* zrow = ((const float4*)zt) + jl * 32;
#pragma unroll 4
  for (int c4 = 0; c4 < 32; ++c4) {
    float4 zv = zrow[c4 ^ (jl & 7)];
    float zq[4] = {zv.x, zv.y, zv.z, zv.w};
#pragma unroll
    for (int q = 0; q < 4; ++q)
#pragma unroll
      for (int u = 0; u < 3; ++u)
        acc[u] += zq[q] * Wb[(c4 * 4 + q) * Hh + h3 + u];
  }

  // ext part: 28-dot (extq uniform -> sgpr, extk per-lane gather)
#pragma unroll
  for (int u = 0; u < 3; ++u) {
    int h = h3 + u;
    const float4* eq4 = (const float4*)(extq + (size_t)(i * Hh + h) * EXT);
    const float4* ek4 = (const float4*)(extk + (size_t)(j * Hh + h) * EXT);
    float d = 0.f;
#pragma unroll
    for (int e = 0; e < 7; ++e) {
      float4 a4 = eq4[e], b4 = ek4[e];
      d += a4.x * b4.x + a4.y * b4.y + a4.z * b4.z + a4.w * b4.w;
    }
    acc[u] += d;
  }
#pragma unroll
  for (int u = 0; u < 3; ++u)
    logits[(size_t)(i * Hh + h3 + u) * Nn + j] = W_L * acc[u];
}

// ================= K3: softmax over j, in place ==============================
__global__ __launch_bounds__(128) void k_softmax(float* __restrict__ logits) {
  int row = blockIdx.x;                            // i*12+h
  int tid = threadIdx.x;
  float4* rp = (float4*)(logits + (size_t)row * Nn);
  float4 v = rp[tid];
  float m = fmaxf(fmaxf(v.x, v.y), fmaxf(v.z, v.w));
#pragma unroll
  for (int k = 32; k >= 1; k >>= 1) m = fmaxf(m, __shfl_xor(m, k));
  __shared__ float red[2][2];
  int wave = tid >> 6, lane = tid & 63;
  if (lane == 0) red[0][wave] = m;
  __syncthreads();
  m = fmaxf(red[0][0], red[0][1]);
  float4 e;
  e.x = __expf(v.x - m); e.y = __expf(v.y - m);
  e.z = __expf(v.z - m); e.w = __expf(v.w - m);
  float s = e.x + e.y + e.z + e.w;
#pragma unroll
  for (int k = 32; k >= 1; k >>= 1) s += __shfl_xor(s, k);
  if (lane == 0) red[1][wave] = s;
  __syncthreads();
  s = red[1][0] + red[1][1];
  float r = 1.f / s;
  e.x *= r; e.y *= r; e.z *= r; e.w *= r;
  rp[tid] = e;
}

// ===== K4: per-i attention apply: o_pair, o_sc, o_pt(+invert)+norm -> feat ===
__global__ __launch_bounds__(512) void k_attend(
    const float* __restrict__ z, const float* __restrict__ a,
    const float* __restrict__ P, const float* __restrict__ vpg,
    const float* __restrict__ rot, const float* __restrict__ trans,
    float* __restrict__ feat) {
  int i = blockIdx.x, tid = threadIdx.x;
  float* Fi = feat + (size_t)i * FIN;
  __shared__ float optg[288];

  // phase A: o_pair[h][c] = sum_j a[h][j] * z[i][j][c]
  {
    int c = tid & 127;
    int hg = __builtin_amdgcn_readfirstlane(tid >> 7);   // 0..3
    const float* zb = z + (size_t)i * Nn * CZ + c;
    const float* ar = a + (size_t)(i * Hh + hg * 3) * Nn;
    float a0 = 0.f, a1 = 0.f, a2 = 0.f;
#pragma unroll 8
    for (int j = 0; j < Nn; ++j) {
      float zv = zb[(size_t)j * CZ];
      a0 += zv * ar[j];
      a1 += zv * ar[Nn + j];
      a2 += zv * ar[2 * Nn + j];
    }
    Fi[(hg * 3 + 0) * CZ + c] = a0;
    Fi[(hg * 3 + 1) * CZ + c] = a1;
    Fi[(hg * 3 + 2) * CZ + c] = a2;
  }

  // phase B: o_sc (192 lanes) and o_pt_g (288 lanes)
  if (tid < 192) {
    int h = tid >> 4;
    const float* ar = a + (size_t)(i * Hh + h) * Nn;
    float acc = 0.f;
#pragma unroll 4
    for (int j = 0; j < Nn; ++j)
      acc += ar[j] * P[(size_t)j * NCOL + 384 + tid];
    Fi[1536 + tid] = acc;
  } else if (tid < 480) {
    int t2 = tid - 192;
    int h = t2 / 24;
    const float* ar = a + (size_t)(i * Hh + h) * Nn;
    float acc = 0.f;
#pragma unroll 4
    for (int j = 0; j < Nn; ++j)
      acc += ar[j] * vpg[(size_t)j * 288 + t2];
    optg[t2] = acc;
  }
  __syncthreads();

  // phase C: invert-apply + norm
  if (tid < 96) {
    int h = tid >> 3, p = tid & 7;
    float g0 = optg[h * 24 + p * 3 + 0] - trans[i * 3 + 0];
    float g1 = optg[h * 24 + p * 3 + 1] - trans[i * 3 + 1];
    float g2 = optg[h * 24 + p * 3 + 2] - trans[i * 3 + 2];
    const float* R = rot + i * 9;
    float ss = 0.f;
#pragma unroll
    for (int nn2 = 0; nn2 < 3; ++nn2) {
      float o = R[nn2] * g0 + R[3 + nn2] * g1 + R[6 + nn2] * g2;   // R^T (g - t)
      Fi[1728 + h * 24 + p * 3 + nn2] = o;
      ss += o * o;
    }
    Fi[2016 + h * 8 + p] = sqrtf(ss + 1e-12f);
  }
}

// ============ K5a: out partials  part[fs][i][o] = feat[f-slice] @ Wf ========
__global__ __launch_bounds__(384) void k_out_partial(
    const float* __restrict__ feat, const float* __restrict__ Wf,
    float* __restrict__ part) {
  int fs = blockIdx.x;                     // 0..7 (f-slice of 264)
  int i0 = blockIdx.y * 8;
  int o = threadIdx.x;                     // 0..383
  float acc[8];
#pragma unroll
  for (int ii = 0; ii < 8; ++ii) acc[ii] = 0.f;
  int f0 = fs * 264;
#pragma unroll 4
  for (int f = f0; f < f0 + 264; ++f) {
    float w = Wf[(size_t)f * CS + o];
#pragma unroll
    for (int ii = 0; ii < 8; ++ii) acc[ii] += w * feat[(size_t)(i0 + ii) * FIN + f];
  }
#pragma unroll
  for (int ii = 0; ii < 8; ++ii)
    part[((size_t)fs * Nn + i0 + ii) * CS + o] = acc[ii];
}

// ============ K5b: reduce partials + bias -> out ============================
__global__ __launch_bounds__(256) void k_out_reduce(
    const float* __restrict__ part, const float* __restrict__ bf,
    float* __restrict__ out) {
  int idx = blockIdx.x * 256 + threadIdx.x;        // < 512*384
  float s = bf[idx % CS];
#pragma unroll
  for (int fs = 0; fs < 8; ++fs) s += part[(size_t)fs * (Nn * CS) + idx];
  out[idx] = s;
}

// ============================ launcher ======================================
extern "C" void kernel_launch(void* const* d_in, const int* in_sizes, int n_in,
                              void* d_out, int out_size, void* d_ws, size_t ws_size,
                              hipStream_t stream) {
  const float* s_i   = (const float*)d_in[0];
  const float* z_ij  = (const float*)d_in[1];
  const float* rot   = (const float*)d_in[2];
  const float* trans = (const float*)d_in[3];
  const float* Wq    = (const float*)d_in[4];
  const float* Wk    = (const float*)d_in[5];
  const float* Wv    = (const float*)d_in[6];
  const float* Wqp   = (const float*)d_in[7];
  const float* Wkp   = (const float*)d_in[8];
  const float* Wvp   = (const float*)d_in[9];
  const float* Wb    = (const float*)d_in[10];
  const float* gamma = (const float*)d_in[11];
  const float* Wf    = (const float*)d_in[12];
  const float* bf    = (const float*)d_in[13];
  float* out = (float*)d_out;

  float* w = (float*)d_ws;
  float* P    = w + OFF_P;
  float* extq = w + OFF_EXTQ;
  float* extk = w + OFF_EXTK;
  float* mq   = w + OFF_MQ;
  float* mk   = w + OFF_MK;
  float* vpg  = w + OFF_VPG;
  float* feat = w + OFF_FEAT;
  float* lg   = w + OFF_LOG;     // logits -> a (in place) -> K5 partials (reuse)

  k_proj<<<dim3(3, 64), 384, 0, stream>>>(s_i, Wq, Wk, Wv, Wqp, Wkp, Wvp, P);
  k_prep<<<96, 64, 0, stream>>>(P, rot, trans, gamma, extq, extk, mq, mk, vpg);
  k_logits<<<dim3(8, 512), 256, 0, stream>>>(z_ij, extq, extk, mq, mk, Wb, lg);
  k_softmax<<<6144, 128, 0, stream>>>(lg);
  k_attend<<<512, 512, 0, stream>>>(z_ij, lg, P, vpg, rot, trans, feat);
  k_out_partial<<<dim3(8, 64), 384, 0, stream>>>(feat, Wf, lg);   // reuse lg as partials
  k_out_reduce<<<768, 256, 0, stream>>>(lg, bf, out);
}